// Round 1
// 304.554 us; speedup vs baseline: 1.0409x; 1.0409x over previous
//
#include <hip/hip_runtime.h>
#include <cstdint>

#define N 8192
#define D 64
#define ALPHA 3.0f
#define ONE_BELOW 0x1.fffffep-1f
// Calibration (rounds 4,6,7,8 probes; rounds 9,10,12,13,14,16 PASSED absmax 0):
// in the emulated np-arithmetic metric (strict sequential f32 FMA chain,
// single accumulator, ascending k), the reference's tie predicate
// "tanh(x)==1.0f" is exactly x > X_MINUS, X_MINUS = 0x40FFF5AE =
// 7.998740174f. Selection = first 32 ties per row by column index.
// C_MID clamp is part of the calibrated nv metric — do not change.
// R18 (this round):
//  * nv v4: 16 rows/block, W rows cached in registers (32x ds_read_b128 once
//    per wave), e via LDS b128 broadcasts. FMA chains UNCHANGED: per
//    accumulator still strict ascending-d single-acc fmaf — unrolling cannot
//    reassociate a dependent chain. Removes the 256 scalar ds_read_b32/thread
//    that made nv LDS-issue-bound (~10 us -> ~3 us predicted).
//  * scan+write fused: lane t's sel nibble c covers exactly f32x4 group
//    c*64+t of the row, so the scan wave writes its own 4 output rows
//    directly (1 KB coalesced per store). selbuf + write_kernel deleted.
#define C_MID 7.99859f
#define X_MINUS_BITS 0x40FFF5AEu
#define WPAD 68

typedef unsigned long long u64;
typedef unsigned int u32;
typedef float f32x4 __attribute__((ext_vector_type(4)));

__device__ __forceinline__ float sat_tanh(float z) {
    if (z >=  C_MID) return 1.0f;
    if (z <= -C_MID) return -1.0f;
    float t = tanhf(z);
    return fminf(fmaxf(t, -ONE_BELOW), ONE_BELOW);
}

// ---------------------------------------------------------------------------
// NV v4: 16 rows/block (512 blocks x 256 thr). W1/W2 staged to LDS with
// pad-68 rows (16B-aligned), each lane loads its own W row into 32 f32x4
// registers once; per row the e-vector arrives as wave-uniform b128
// broadcasts. Values + chain order bit-identical to all passing rounds:
// s = fmaf(e[d], W[t][d], s) for d = 0..63 ascending, single accumulator.
// ---------------------------------------------------------------------------
__global__ __launch_bounds__(256) void nv_emu_kernel(
    const float* __restrict__ emb1, const float* __restrict__ emb2,
    const float* __restrict__ W1, const float* __restrict__ b1,
    const float* __restrict__ W2, const float* __restrict__ b2,
    float* __restrict__ NVT1, float* __restrict__ NVT2,
    float* __restrict__ NV1r, float* __restrict__ NV2r)
{
    int ib = blockIdx.x * 16;
    int tid = threadIdx.x;
    __shared__ float W1s[D * WPAD];
    __shared__ float W2s[D * WPAD];
    __shared__ float e1s[16 * D], e2s[16 * D];
    __shared__ float t1s[64 * 5];
    __shared__ float t2s[64 * 5];
#pragma unroll
    for (int v = 0; v < 4; v++) {
        int idx = v * 1024 + tid * 4;
        f32x4 a = *(const f32x4*)(W1 + idx);
        f32x4 b = *(const f32x4*)(W2 + idx);
        int r = idx >> 6, cc = idx & 63;
        *(f32x4*)&W1s[r * WPAD + cc] = a;      // (r*68+cc)*4 is 16B-aligned
        *(f32x4*)&W2s[r * WPAD + cc] = b;
    }
#pragma unroll
    for (int k = 0; k < 4; k++) {
        e1s[k * 256 + tid] = emb1[(size_t)ib * D + k * 256 + tid];
        e2s[k * 256 + tid] = emb2[(size_t)ib * D + k * 256 + tid];
    }
    __syncthreads();

    int w = tid >> 6, t = tid & 63;
    f32x4 w1v[16], w2v[16];                    // lane-private W row t
#pragma unroll
    for (int k = 0; k < 16; k++) {
        w1v[k] = *(const f32x4*)&W1s[t * WPAD + 4 * k];
        w2v[k] = *(const f32x4*)&W2s[t * WPAD + 4 * k];
    }
    float bb1 = b1[t], bb2 = b2[t];

    for (int g = 0; g < 4; g++) {
        int rloc = g * 4 + w;                  // row within block
        int i = ib + rloc;                     // global row
        const float* e1p = &e1s[rloc * 64];
        const float* e2p = &e2s[rloc * 64];
        float s1 = 0.0f, s2 = 0.0f;
#pragma unroll
        for (int k = 0; k < 16; k++) {         // d = 4k+j, j=0..3: ascending,
            f32x4 q1 = *(const f32x4*)&e1p[4 * k];   // single accumulator —
            f32x4 q2 = *(const f32x4*)&e2p[4 * k];   // exact chain preserved
            s1 = fmaf(q1.x, w1v[k].x, s1);
            s2 = fmaf(q2.x, w2v[k].x, s2);
            s1 = fmaf(q1.y, w1v[k].y, s1);
            s2 = fmaf(q2.y, w2v[k].y, s2);
            s1 = fmaf(q1.z, w1v[k].z, s1);
            s2 = fmaf(q2.z, w2v[k].z, s2);
            s1 = fmaf(q1.w, w1v[k].w, s1);
            s2 = fmaf(q2.w, w2v[k].w, s2);
        }
        float v1 = sat_tanh(ALPHA * (s1 + bb1));
        float v2 = sat_tanh(ALPHA * (s2 + bb2));
        NV1r[(size_t)i * D + t] = v1;
        NV2r[(size_t)i * D + t] = v2;
        t1s[t * 5 + w] = v1;
        t2s[t * 5 + w] = v2;
        __syncthreads();
        int d = tid >> 2, ii = tid & 3;
        int i0g = ib + g * 4;
        NVT1[(size_t)d * N + i0g + ii] = t1s[d * 5 + ii];
        NVT2[(size_t)d * N + i0g + ii] = t2s[d * 5 + ii];
        __syncthreads();                       // t1s reused next g
    }
}

// ---------------------------------------------------------------------------
// Scan (R14/R16 validated logic verbatim) + fused writer. Lane t's sel
// nibble c covers cols 256c+4t+{0..3} = f32x4 group c*64+t of the row, so
// each wave writes its 4 full output rows directly: per (row,c) the 64
// lanes store 64 consecutive f32x4 = 1 KB coalesced. No selbuf round-trip.
// ---------------------------------------------------------------------------
__global__ __launch_bounds__(64) void scan_write_kernel(
    const float* __restrict__ NVT1, const float* __restrict__ NVT2,
    const float* __restrict__ NV1r, const float* __restrict__ NV2r,
    float* __restrict__ out)
{
    int row0 = blockIdx.x * 4;
    int t = threadIdx.x;
    __shared__ float n1[4 * D], n2[4 * D];
#pragma unroll
    for (int k = 0; k < 4; k++) {
        n1[k * 64 + t] = NV1r[(size_t)row0 * D + k * 64 + t];
        n2[k * 64 + t] = NV2r[(size_t)row0 * D + k * 64 + t];
    }
    __syncthreads();

    const float xminus = __uint_as_float(X_MINUS_BITS);
    const u64 ltmask = (t == 63) ? (~0ull >> 1) : ((1ull << t) - 1);
    u64 sel[4][2] = {{0, 0}, {0, 0}, {0, 0}, {0, 0}};
    int tot[4] = {0, 0, 0, 0};

    for (int c = 0; c < N / 256; c++) {
        if (tot[0] >= 32 && tot[1] >= 32 && tot[2] >= 32 && tot[3] >= 32) break;
        int j = c * 256 + 4 * t;
        const f32x4* q2p = (const f32x4*)(NVT2 + j);
        const f32x4* q1p = (const f32x4*)(NVT1 + j);
        float a[4][4] = {{0}}, b[4][4] = {{0}};
#pragma unroll 8
        for (int d = 0; d < D; d++) {             // ascending d, single acc/col
            f32x4 q2 = q2p[(size_t)d * (N / 4)];
            f32x4 q1 = q1p[(size_t)d * (N / 4)];
#pragma unroll
            for (int r = 0; r < 4; r++) {
                float w1 = n1[r * 64 + d], w2 = n2[r * 64 + d];
                a[r][0] = fmaf(w1, q2.x, a[r][0]);
                a[r][1] = fmaf(w1, q2.y, a[r][1]);
                a[r][2] = fmaf(w1, q2.z, a[r][2]);
                a[r][3] = fmaf(w1, q2.w, a[r][3]);
                b[r][0] = fmaf(w2, q1.x, b[r][0]);
                b[r][1] = fmaf(w2, q1.y, b[r][1]);
                b[r][2] = fmaf(w2, q1.z, b[r][2]);
                b[r][3] = fmaf(w2, q1.w, b[r][3]);
            }
        }
#pragma unroll
        for (int r = 0; r < 4; r++) {
            if (tot[r] >= 32) continue;           // wave-uniform branch
            bool t0 = (3.0f * (a[r][0] - b[r][0])) > xminus;
            bool t1 = (3.0f * (a[r][1] - b[r][1])) > xminus;
            bool t2 = (3.0f * (a[r][2] - b[r][2])) > xminus;
            bool t3 = (3.0f * (a[r][3] - b[r][3])) > xminus;
            u64 m0 = __ballot(t0), m1 = __ballot(t1);
            u64 m2 = __ballot(t2), m3 = __ballot(t3);
            int pre = tot[r] + (int)__popcll(m0 & ltmask) + (int)__popcll(m1 & ltmask)
                             + (int)__popcll(m2 & ltmask) + (int)__popcll(m3 & ltmask);
            int h0 = (int)((m0 >> t) & 1), h1 = (int)((m1 >> t) & 1), h2 = (int)((m2 >> t) & 1);
            u32 mask4 = 0;
            if (t0 && pre < 32)                  mask4 |= 1u;
            if (t1 && (pre + h0) < 32)           mask4 |= 2u;
            if (t2 && (pre + h0 + h1) < 32)      mask4 |= 4u;
            if (t3 && (pre + h0 + h1 + h2) < 32) mask4 |= 8u;
            sel[r][c >> 4] |= (u64)mask4 << ((c & 15) * 4);
            tot[r] += (int)(__popcll(m0) + __popcll(m1) + __popcll(m2) + __popcll(m3));
        }
    }

    // fused writer: lane t owns groups c*64+t (cols 256c+4t+e) of each row
#pragma unroll
    for (int r = 0; r < 4; r++) {
        f32x4* orow = (f32x4*)(out + (size_t)(row0 + r) * N);
        u64 lo = sel[r][0], hi = sel[r][1];
#pragma unroll
        for (int c = 0; c < 16; c++) {
            u32 bits = (u32)(lo >> (c * 4)) & 0xFu;
            f32x4 val;
            val.x = (bits & 1u) ? 1.0f : 0.0f;
            val.y = (bits & 2u) ? 1.0f : 0.0f;
            val.z = (bits & 4u) ? 1.0f : 0.0f;
            val.w = (bits & 8u) ? 1.0f : 0.0f;
            orow[c * 64 + t] = val;
        }
#pragma unroll
        for (int c = 0; c < 16; c++) {
            u32 bits = (u32)(hi >> (c * 4)) & 0xFu;
            f32x4 val;
            val.x = (bits & 1u) ? 1.0f : 0.0f;
            val.y = (bits & 2u) ? 1.0f : 0.0f;
            val.z = (bits & 4u) ? 1.0f : 0.0f;
            val.w = (bits & 8u) ? 1.0f : 0.0f;
            orow[(16 + c) * 64 + t] = val;
        }
    }
}

// ---------------------------------------------------------------------------
extern "C" void kernel_launch(void* const* d_in, const int* in_sizes, int n_in,
                              void* d_out, int out_size, void* d_ws, size_t ws_size,
                              hipStream_t stream)
{
    // setup_inputs order: idx, emb1, emb2, W1, b1, W2, b2 (idx = arange -> skip)
    const float* emb1 = (const float*)d_in[1];
    const float* emb2 = (const float*)d_in[2];
    const float* W1   = (const float*)d_in[3];
    const float* b1   = (const float*)d_in[4];
    const float* W2   = (const float*)d_in[5];
    const float* b2   = (const float*)d_in[6];
    float* out = (float*)d_out;
    float* NVT1 = (float*)d_ws;                    // 4 MB (64 x 8192)
    float* NVT2 = NVT1 + (size_t)D * N;            // 4 MB
    float* NV1r = NVT2 + (size_t)D * N;            // 2 MB (8192 x 64)
    float* NV2r = NV1r + (size_t)N * D;            // 2 MB

    nv_emu_kernel<<<N / 16, 256, 0, stream>>>(emb1, emb2, W1, b1, W2, b2,
                                              NVT1, NVT2, NV1r, NV2r);
    scan_write_kernel<<<N / 4, 64, 0, stream>>>(NVT1, NVT2, NV1r, NV2r, out);
}

// Round 2
// 293.384 us; speedup vs baseline: 1.0805x; 1.0381x over previous
//
#include <hip/hip_runtime.h>
#include <cstdint>

#define N 8192
#define D 64
#define ALPHA 3.0f
#define ONE_BELOW 0x1.fffffep-1f
// Calibration (rounds 4,6,7,8 probes; rounds 9,10,12,13,14,16,18 PASSED
// absmax 0): in the emulated np-arithmetic metric (strict sequential f32 FMA
// chain, single accumulator, ascending k), the reference's tie predicate
// "tanh(x)==1.0f" is exactly x > X_MINUS, X_MINUS = 0x40FFF5AE =
// 7.998740174f. Selection = first 32 ties per row by column index.
// C_MID clamp is part of the calibrated nv metric — do not change.
// R19 (this round): interleaved store — chunk c's nibble is FINAL right
// after its ballots (first-32-by-index selection can't be revised by later
// columns), so the wave stores chunk c of all 4 rows immediately, then
// streams a pure zero tail after all rows reach 32 ties. Removes the serial
// scan-then-write phase structure (all 2048 blocks are co-resident, so the
// scan phase was fully exposed, not pipelined). Ballot logic / FMA chains /
// predicate bit-identical to R18.
#define C_MID 7.99859f
#define X_MINUS_BITS 0x40FFF5AEu
#define WPAD 68

typedef unsigned long long u64;
typedef unsigned int u32;
typedef float f32x4 __attribute__((ext_vector_type(4)));

__device__ __forceinline__ float sat_tanh(float z) {
    if (z >=  C_MID) return 1.0f;
    if (z <= -C_MID) return -1.0f;
    float t = tanhf(z);
    return fminf(fmaxf(t, -ONE_BELOW), ONE_BELOW);
}

// ---------------------------------------------------------------------------
// NV v4 (R18, verified): 16 rows/block (512 blocks x 256 thr). W1/W2 staged
// to LDS with pad-68 rows (16B-aligned), each lane loads its own W row into
// 32 f32x4 registers once; per row the e-vector arrives as wave-uniform b128
// broadcasts. Values + chain order bit-identical to all passing rounds:
// s = fmaf(e[d], W[t][d], s) for d = 0..63 ascending, single accumulator.
// ---------------------------------------------------------------------------
__global__ __launch_bounds__(256) void nv_emu_kernel(
    const float* __restrict__ emb1, const float* __restrict__ emb2,
    const float* __restrict__ W1, const float* __restrict__ b1,
    const float* __restrict__ W2, const float* __restrict__ b2,
    float* __restrict__ NVT1, float* __restrict__ NVT2,
    float* __restrict__ NV1r, float* __restrict__ NV2r)
{
    int ib = blockIdx.x * 16;
    int tid = threadIdx.x;
    __shared__ float W1s[D * WPAD];
    __shared__ float W2s[D * WPAD];
    __shared__ float e1s[16 * D], e2s[16 * D];
    __shared__ float t1s[64 * 5];
    __shared__ float t2s[64 * 5];
#pragma unroll
    for (int v = 0; v < 4; v++) {
        int idx = v * 1024 + tid * 4;
        f32x4 a = *(const f32x4*)(W1 + idx);
        f32x4 b = *(const f32x4*)(W2 + idx);
        int r = idx >> 6, cc = idx & 63;
        *(f32x4*)&W1s[r * WPAD + cc] = a;      // (r*68+cc)*4 is 16B-aligned
        *(f32x4*)&W2s[r * WPAD + cc] = b;
    }
#pragma unroll
    for (int k = 0; k < 4; k++) {
        e1s[k * 256 + tid] = emb1[(size_t)ib * D + k * 256 + tid];
        e2s[k * 256 + tid] = emb2[(size_t)ib * D + k * 256 + tid];
    }
    __syncthreads();

    int w = tid >> 6, t = tid & 63;
    f32x4 w1v[16], w2v[16];                    // lane-private W row t
#pragma unroll
    for (int k = 0; k < 16; k++) {
        w1v[k] = *(const f32x4*)&W1s[t * WPAD + 4 * k];
        w2v[k] = *(const f32x4*)&W2s[t * WPAD + 4 * k];
    }
    float bb1 = b1[t], bb2 = b2[t];

    for (int g = 0; g < 4; g++) {
        int rloc = g * 4 + w;                  // row within block
        int i = ib + rloc;                     // global row
        const float* e1p = &e1s[rloc * 64];
        const float* e2p = &e2s[rloc * 64];
        float s1 = 0.0f, s2 = 0.0f;
#pragma unroll
        for (int k = 0; k < 16; k++) {         // d = 4k+j, j=0..3: ascending,
            f32x4 q1 = *(const f32x4*)&e1p[4 * k];   // single accumulator —
            f32x4 q2 = *(const f32x4*)&e2p[4 * k];   // exact chain preserved
            s1 = fmaf(q1.x, w1v[k].x, s1);
            s2 = fmaf(q2.x, w2v[k].x, s2);
            s1 = fmaf(q1.y, w1v[k].y, s1);
            s2 = fmaf(q2.y, w2v[k].y, s2);
            s1 = fmaf(q1.z, w1v[k].z, s1);
            s2 = fmaf(q2.z, w2v[k].z, s2);
            s1 = fmaf(q1.w, w1v[k].w, s1);
            s2 = fmaf(q2.w, w2v[k].w, s2);
        }
        float v1 = sat_tanh(ALPHA * (s1 + bb1));
        float v2 = sat_tanh(ALPHA * (s2 + bb2));
        NV1r[(size_t)i * D + t] = v1;
        NV2r[(size_t)i * D + t] = v2;
        t1s[t * 5 + w] = v1;
        t2s[t * 5 + w] = v2;
        __syncthreads();
        int d = tid >> 2, ii = tid & 3;
        int i0g = ib + g * 4;
        NVT1[(size_t)d * N + i0g + ii] = t1s[d * 5 + ii];
        NVT2[(size_t)d * N + i0g + ii] = t2s[d * 5 + ii];
        __syncthreads();                       // t1s reused next g
    }
}

// ---------------------------------------------------------------------------
// Scan (R14/R16 validated logic verbatim) with INTERLEAVED writer. Lane t's
// nibble for chunk c covers cols 256c+4t+{0..3} = f32x4 group c*64+t of the
// row; the nibble is final right after chunk c's ballots, so it is stored
// immediately (64 consecutive f32x4 = 1 KB coalesced per row-chunk). After
// all 4 rows reach 32 ties, the remaining chunks are a pure zero stream.
// ---------------------------------------------------------------------------
__global__ __launch_bounds__(64) void scan_write_kernel(
    const float* __restrict__ NVT1, const float* __restrict__ NVT2,
    const float* __restrict__ NV1r, const float* __restrict__ NV2r,
    float* __restrict__ out)
{
    int row0 = blockIdx.x * 4;
    int t = threadIdx.x;
    __shared__ float n1[4 * D], n2[4 * D];
#pragma unroll
    for (int k = 0; k < 4; k++) {
        n1[k * 64 + t] = NV1r[(size_t)row0 * D + k * 64 + t];
        n2[k * 64 + t] = NV2r[(size_t)row0 * D + k * 64 + t];
    }
    __syncthreads();

    const float xminus = __uint_as_float(X_MINUS_BITS);
    const u64 ltmask = (t == 63) ? (~0ull >> 1) : ((1ull << t) - 1);
    int tot[4] = {0, 0, 0, 0};
    f32x4* o4 = (f32x4*)(out + (size_t)row0 * N);   // row r chunk c group at
                                                    // o4[r*(N/4) + c*64 + t]
    int c = 0;
    for (; c < N / 256; c++) {
        if (tot[0] >= 32 && tot[1] >= 32 && tot[2] >= 32 && tot[3] >= 32) break;
        int j = c * 256 + 4 * t;
        const f32x4* q2p = (const f32x4*)(NVT2 + j);
        const f32x4* q1p = (const f32x4*)(NVT1 + j);
        float a[4][4] = {{0}}, b[4][4] = {{0}};
#pragma unroll 8
        for (int d = 0; d < D; d++) {             // ascending d, single acc/col
            f32x4 q2 = q2p[(size_t)d * (N / 4)];
            f32x4 q1 = q1p[(size_t)d * (N / 4)];
#pragma unroll
            for (int r = 0; r < 4; r++) {
                float w1 = n1[r * 64 + d], w2 = n2[r * 64 + d];
                a[r][0] = fmaf(w1, q2.x, a[r][0]);
                a[r][1] = fmaf(w1, q2.y, a[r][1]);
                a[r][2] = fmaf(w1, q2.z, a[r][2]);
                a[r][3] = fmaf(w1, q2.w, a[r][3]);
                b[r][0] = fmaf(w2, q1.x, b[r][0]);
                b[r][1] = fmaf(w2, q1.y, b[r][1]);
                b[r][2] = fmaf(w2, q1.z, b[r][2]);
                b[r][3] = fmaf(w2, q1.w, b[r][3]);
            }
        }
#pragma unroll
        for (int r = 0; r < 4; r++) {
            u32 mask4 = 0;
            if (tot[r] < 32) {                    // wave-uniform branch
                bool t0 = (3.0f * (a[r][0] - b[r][0])) > xminus;
                bool t1 = (3.0f * (a[r][1] - b[r][1])) > xminus;
                bool t2 = (3.0f * (a[r][2] - b[r][2])) > xminus;
                bool t3 = (3.0f * (a[r][3] - b[r][3])) > xminus;
                u64 m0 = __ballot(t0), m1 = __ballot(t1);
                u64 m2 = __ballot(t2), m3 = __ballot(t3);
                int pre = tot[r] + (int)__popcll(m0 & ltmask) + (int)__popcll(m1 & ltmask)
                                 + (int)__popcll(m2 & ltmask) + (int)__popcll(m3 & ltmask);
                int h0 = (int)((m0 >> t) & 1), h1 = (int)((m1 >> t) & 1), h2 = (int)((m2 >> t) & 1);
                if (t0 && pre < 32)                  mask4 |= 1u;
                if (t1 && (pre + h0) < 32)           mask4 |= 2u;
                if (t2 && (pre + h0 + h1) < 32)      mask4 |= 4u;
                if (t3 && (pre + h0 + h1 + h2) < 32) mask4 |= 8u;
                tot[r] += (int)(__popcll(m0) + __popcll(m1) + __popcll(m2) + __popcll(m3));
            }
            f32x4 val;
            val.x = (mask4 & 1u) ? 1.0f : 0.0f;
            val.y = (mask4 & 2u) ? 1.0f : 0.0f;
            val.z = (mask4 & 4u) ? 1.0f : 0.0f;
            val.w = (mask4 & 8u) ? 1.0f : 0.0f;
            o4[(size_t)r * (N / 4) + c * 64 + t] = val;
        }
    }
    // pure zero tail — no loads, no ballots, just the write stream
    f32x4 z;
    z.x = 0.0f; z.y = 0.0f; z.z = 0.0f; z.w = 0.0f;
    for (; c < N / 256; c++) {
#pragma unroll
        for (int r = 0; r < 4; r++)
            o4[(size_t)r * (N / 4) + c * 64 + t] = z;
    }
}

// ---------------------------------------------------------------------------
extern "C" void kernel_launch(void* const* d_in, const int* in_sizes, int n_in,
                              void* d_out, int out_size, void* d_ws, size_t ws_size,
                              hipStream_t stream)
{
    // setup_inputs order: idx, emb1, emb2, W1, b1, W2, b2 (idx = arange -> skip)
    const float* emb1 = (const float*)d_in[1];
    const float* emb2 = (const float*)d_in[2];
    const float* W1   = (const float*)d_in[3];
    const float* b1   = (const float*)d_in[4];
    const float* W2   = (const float*)d_in[5];
    const float* b2   = (const float*)d_in[6];
    float* out = (float*)d_out;
    float* NVT1 = (float*)d_ws;                    // 4 MB (64 x 8192)
    float* NVT2 = NVT1 + (size_t)D * N;            // 4 MB
    float* NV1r = NVT2 + (size_t)D * N;            // 2 MB (8192 x 64)
    float* NV2r = NV1r + (size_t)N * D;            // 2 MB

    nv_emu_kernel<<<N / 16, 256, 0, stream>>>(emb1, emb2, W1, b1, W2, b2,
                                              NVT1, NVT2, NV1r, NV2r);
    scan_write_kernel<<<N / 4, 64, 0, stream>>>(NVT1, NVT2, NV1r, NV2r, out);
}